// Round 18
// baseline (19.139 us; speedup 1.0000x reference)
//
#include <hip/hip_runtime.h>

// Fasttext: out[b,t,p] = W @ embed[ids[b,t]] + b, masked t < seq_lengths[b]
// VOCAB=200000, E=300, P=128, B=16, S=2048, BS=32768
//
// R21 = R20 (18.76us) + __launch_bounds__(256,4): cap VGPR at 128 to lift
// occupancy 3 -> 4 waves/SIMD (12 -> 16 waves/CU) while keeping the full
// 20-deep raw-first gather burst (80 VGPR homogeneous array + ~35 misc
// fits 128 by hand count; av[10] reuses dying burst regs). The (waves x
// depth) product is the governing quantity (R9/R17/R18/R20 ledger); this
// is its last unexplored cell. If the allocator spills, expect >=20us and
// revert. Everything else identical to R20: packed real tiles + XCD
// pairing, W-half fragment-major 40KB LDS, raw burst before W staging,
// balanced zero-fill, exact-bounds tails.

#define E 300
#define P 128
#define S 2048
#define BS 32768
#define TM 64
#define NB 16

typedef short bf16x8 __attribute__((ext_vector_type(8)));
typedef short bf16x4 __attribute__((ext_vector_type(4)));
typedef float f32x4 __attribute__((ext_vector_type(4)));

__device__ inline unsigned short f32_bf16_fast(float f) {
    unsigned int u = __builtin_bit_cast(unsigned int, f);
    return (unsigned short)((u + 0x8000u) >> 16);
}
__device__ inline bf16x8 cvt8(f32x4 a, f32x4 b) {
    bf16x8 r;
    r[0] = (short)f32_bf16_fast(a[0]); r[1] = (short)f32_bf16_fast(a[1]);
    r[2] = (short)f32_bf16_fast(a[2]); r[3] = (short)f32_bf16_fast(a[3]);
    r[4] = (short)f32_bf16_fast(b[0]); r[5] = (short)f32_bf16_fast(b[1]);
    r[6] = (short)f32_bf16_fast(b[2]); r[7] = (short)f32_bf16_fast(b[3]);
    return r;
}
__device__ inline bf16x4 cvt4(f32x4 a) {
    bf16x4 r;
    r[0] = (short)f32_bf16_fast(a[0]); r[1] = (short)f32_bf16_fast(a[1]);
    r[2] = (short)f32_bf16_fast(a[2]); r[3] = (short)f32_bf16_fast(a[3]);
    return r;
}

__global__ __launch_bounds__(256, 4) void ft_main(
    const int* __restrict__ ids, const int* __restrict__ seqlen,
    const float* __restrict__ embed, const float* __restrict__ Wf,
    const float* __restrict__ bias, float* __restrict__ out)
{
    __shared__ unsigned char Wl[40960];

    const int tid  = threadIdx.x;
    const int wave = tid >> 6, lane = tid & 63;
    const int fr   = lane & 15, kg = lane >> 4;
    const int d    = blockIdx.x;                 // [0, 1024)

    // slot -> (real-tile index rt, col-half ch); pair (d, d+8) same XCD
    const int grp = d >> 4, sub = d & 15;
    const int rt  = grp * 8 + (sub & 7);         // [0, 512)
    const int ch  = sub >> 3;

    // locate rt among real tiles: batch b, local tile lt (register-only scan)
    int b = -1, lt = 0, acc = 0;
    #pragma unroll
    for (int bb = 0; bb < NB; ++bb) {
        int rb = (seqlen[bb] + 63) >> 6;         // real tiles in batch bb
        if (rt >= acc && rt < acc + rb) { b = bb; lt = rt - acc; }
        acc += rb;
    }

    if (b >= 0) {                                 // ---- real GEMM block ----
        const int tok0 = (b << 11) + (lt << 6);
        const int sl0  = seqlen[b];

        // -- A: id, then issue the ENTIRE gather burst (20 loads, no VALU) --
        const int token_a = tok0 + wave * 16 + fr;
        const int id = ids[token_a];
        const float* __restrict__ rp = embed + (long long)id * E;

        f32x4 r0[9], r1[9], t0v, t1v;
        #pragma unroll
        for (int s = 0; s < 9; ++s) {
            const int kb = s * 32 + kg * 8;       // <= 280; ends 287 < 300
            r0[s] = *(const f32x4*)(rp + kb);
            r1[s] = *(const f32x4*)(rp + kb + 4);
        }
        {   // tail loads: valid k 288..299, exact bounds
            f32x4 z4 = {0.f, 0.f, 0.f, 0.f};
            t0v = z4; t1v = z4;
            if (kg == 0)      { t0v = *(const f32x4*)(rp + 288); t1v = *(const f32x4*)(rp + 292); }
            else if (kg == 1) { t0v = *(const f32x4*)(rp + 296); }
        }

        // -- stage W rows [ch*64, +64) -> LDS fragment-major (overlaps gather) --
        const int R0 = ch * 64;
        #pragma unroll
        for (int i = 0; i < 20; ++i) {
            int g4 = tid + i * 256;               // [0, 5120) quads
            int r  = g4 / 80;
            int c4 = g4 - r * 80;
            int c0 = c4 * 4;                      // {0,4,...,316}
            f32x4 v = {0.f, 0.f, 0.f, 0.f};
            if (c0 < 300)                         // c0 <= 296: reads 296..299 exact
                v = *(const f32x4*)(Wf + (long long)(R0 + r) * E + c0);
            int s   = c0 >> 5;
            int kgg = (c0 & 31) >> 3;
            int h   = (c0 >> 2) & 1;
            int ni  = r >> 4;
            int fr2 = r & 15;
            int off = (((s * 4 + ni) * 16 + fr2) << 6) + (kgg << 4) + (h << 3);
            *(bf16x4*)(Wl + off) = cvt4(v);
        }

        // -- convert the gather burst to bf16 fragments --
        bf16x8 av[10];
        #pragma unroll
        for (int s = 0; s < 9; ++s) av[s] = cvt8(r0[s], r1[s]);
        av[9] = cvt8(t0v, t1v);
        __syncthreads();

        // -- MFMA: 10 k-steps x 4 ni, B from LDS (conflict-free b128) --
        f32x4 acc4[4];
        #pragma unroll
        for (int ni = 0; ni < 4; ++ni) acc4[ni] = (f32x4){0.f, 0.f, 0.f, 0.f};

        #pragma unroll
        for (int s = 0; s < 10; ++s) {
            #pragma unroll
            for (int ni = 0; ni < 4; ++ni) {
                bf16x8 bv = *(const bf16x8*)(Wl + ((((s * 4 + ni) * 16 + fr) << 6) + (kg << 4)));
                acc4[ni] = __builtin_amdgcn_mfma_f32_16x16x32_bf16(av[s], bv, acc4[ni], 0, 0, 0);
            }
        }

        // -- epilogue: +bias, per-row seq-mask, store --
        // C/D layout: col(=W row -> P) = lane&15, row(=token) = (lane>>4)*4 + j
        float bs[4];
        #pragma unroll
        for (int ni = 0; ni < 4; ++ni) bs[ni] = bias[ch * 64 + ni * 16 + fr];

        #pragma unroll
        for (int j = 0; j < 4; ++j) {
            int orow  = wave * 16 + kg * 4 + j;
            int token = tok0 + orow;
            int t     = token & (S - 1);
            bool valid = (t < sl0);
            #pragma unroll
            for (int ni = 0; ni < 4; ++ni) {
                float v = valid ? (acc4[ni][j] + bs[ni]) : 0.0f;
                out[(long long)token * P + ch * 64 + ni * 16 + fr] = v;
            }
        }
    }

    // ---- zero-fill share (ALL blocks, exactly even split) ----
    int rb0  = (seqlen[0]  + 63) >> 6,  rb1  = (seqlen[1]  + 63) >> 6,
        rb2  = (seqlen[2]  + 63) >> 6,  rb3  = (seqlen[3]  + 63) >> 6,
        rb4  = (seqlen[4]  + 63) >> 6,  rb5  = (seqlen[5]  + 63) >> 6,
        rb6  = (seqlen[6]  + 63) >> 6,  rb7  = (seqlen[7]  + 63) >> 6,
        rb8  = (seqlen[8]  + 63) >> 6,  rb9  = (seqlen[9]  + 63) >> 6,
        rb10 = (seqlen[10] + 63) >> 6,  rb11 = (seqlen[11] + 63) >> 6,
        rb12 = (seqlen[12] + 63) >> 6,  rb13 = (seqlen[13] + 63) >> 6,
        rb14 = (seqlen[14] + 63) >> 6,  rb15 = (seqlen[15] + 63) >> 6;
    int zp0 = 0;
    int zp1  = zp0  + ((S - (rb0  << 6)) << 5);
    int zp2  = zp1  + ((S - (rb1  << 6)) << 5);
    int zp3  = zp2  + ((S - (rb2  << 6)) << 5);
    int zp4  = zp3  + ((S - (rb3  << 6)) << 5);
    int zp5  = zp4  + ((S - (rb4  << 6)) << 5);
    int zp6  = zp5  + ((S - (rb5  << 6)) << 5);
    int zp7  = zp6  + ((S - (rb6  << 6)) << 5);
    int zp8  = zp7  + ((S - (rb7  << 6)) << 5);
    int zp9  = zp8  + ((S - (rb8  << 6)) << 5);
    int zp10 = zp9  + ((S - (rb9  << 6)) << 5);
    int zp11 = zp10 + ((S - (rb10 << 6)) << 5);
    int zp12 = zp11 + ((S - (rb11 << 6)) << 5);
    int zp13 = zp12 + ((S - (rb12 << 6)) << 5);
    int zp14 = zp13 + ((S - (rb13 << 6)) << 5);
    int zp15 = zp14 + ((S - (rb14 << 6)) << 5);
    int zp16 = zp15 + ((S - (rb15 << 6)) << 5);

    const int zq  = zp16;
    const int per = (zq + 1023) >> 10;           // quads per block
    int q0 = d * per;
    int q1 = q0 + per; if (q1 > zq) q1 = zq;

    for (int q = q0 + tid; q < q1; q += 256) {
        int base = 0, tk0 = 0;
        #define ZSEL(BB, LO, HI, RB) \
            if (q >= (LO) && q < (HI)) { base = (LO); tk0 = ((BB) << 11) + ((RB) << 6); }
        ZSEL(0,  zp0,  zp1,  rb0)  ZSEL(1,  zp1,  zp2,  rb1)
        ZSEL(2,  zp2,  zp3,  rb2)  ZSEL(3,  zp3,  zp4,  rb3)
        ZSEL(4,  zp4,  zp5,  rb4)  ZSEL(5,  zp5,  zp6,  rb5)
        ZSEL(6,  zp6,  zp7,  rb6)  ZSEL(7,  zp7,  zp8,  rb7)
        ZSEL(8,  zp8,  zp9,  rb8)  ZSEL(9,  zp9,  zp10, rb9)
        ZSEL(10, zp10, zp11, rb10) ZSEL(11, zp11, zp12, rb11)
        ZSEL(12, zp12, zp13, rb12) ZSEL(13, zp13, zp14, rb13)
        ZSEL(14, zp14, zp15, rb14) ZSEL(15, zp15, zp16, rb15)
        #undef ZSEL
        int lq    = q - base;
        int token = tk0 + (lq >> 5);
        int c     = (lq & 31) << 2;
        *(f32x4*)(out + (long long)token * P + c) = (f32x4){0.f, 0.f, 0.f, 0.f};
    }
}

extern "C" void kernel_launch(void* const* d_in, const int* in_sizes, int n_in,
                              void* d_out, int out_size, void* d_ws, size_t ws_size,
                              hipStream_t stream) {
    const int*   ids    = (const int*)d_in[0];
    const int*   sl     = (const int*)d_in[1];
    const float* embed  = (const float*)d_in[2];
    const float* W      = (const float*)d_in[3];
    const float* bias   = (const float*)d_in[4];
    float*       out    = (float*)d_out;

    ft_main<<<(BS / TM) * 2, 256, 0, stream>>>(ids, sl, embed, W, bias, out);
}

// Round 19
// 18.996 us; speedup vs baseline: 1.0075x; 1.0075x over previous
//
#include <hip/hip_runtime.h>

// Fasttext: out[b,t,p] = W @ embed[ids[b,t]] + b, masked t < seq_lengths[b]
// VOCAB=200000, E=300, P=128, B=16, S=2048, BS=32768
//
// FINAL (= R20, best measured 18.76us). R21's VGPR cap regressed -> the
// per-CU VMEM outstanding-request limit, not occupancy, is binding.
// Structure and why each piece is there (session ledger):
//  * single launch (R6: two-kernel graph cost ~1.5us)
//  * W-half staged per block into 40KB LDS, bf16 FRAGMENT-MAJOR so every
//    B-read is one conflict-free ds_read_b128 (R8: strided global W
//    re-reads were the invariant 13us cost of R1-R6)
//  * XCD-pairing swizzle: slots d,d+8 = one tile's two col-halves -> same
//    dispatch slot mod 8 -> same XCD -> the duplicate 77KB/tile gather
//    hits the sibling's L2 (R13: -2.6us)
//  * mask-aware packing: real tiles packed into the first 2R slots via a
//    register-only prefix scan over seq_lengths; masked zero-region split
//    exactly evenly over all 1024 blocks (R15)
//  * raw-first gather burst: all 20 A-loads issued back-to-back into raw
//    f32x4 regs with no interleaved VALU, cvt afterward -> max per-wave
//    load depth (R20: -1.2us; depth confirmed independent lever by R17)
//  * exact-bounds tails everywhere; epilogue masks partial tiles.
// Latency-bound ceiling: random 1.2KB-row gather from HBM-cold 240MB table
// saturates the VMEM queue at ~3TB/s effective (R21: more in-flight
// capacity did not help) -> ~15-19us envelope; this kernel sits at 18.8.

#define E 300
#define P 128
#define S 2048
#define BS 32768
#define TM 64
#define NB 16

typedef short bf16x8 __attribute__((ext_vector_type(8)));
typedef short bf16x4 __attribute__((ext_vector_type(4)));
typedef float f32x4 __attribute__((ext_vector_type(4)));

__device__ inline unsigned short f32_bf16_fast(float f) {
    unsigned int u = __builtin_bit_cast(unsigned int, f);
    return (unsigned short)((u + 0x8000u) >> 16);
}
__device__ inline bf16x8 cvt8(f32x4 a, f32x4 b) {
    bf16x8 r;
    r[0] = (short)f32_bf16_fast(a[0]); r[1] = (short)f32_bf16_fast(a[1]);
    r[2] = (short)f32_bf16_fast(a[2]); r[3] = (short)f32_bf16_fast(a[3]);
    r[4] = (short)f32_bf16_fast(b[0]); r[5] = (short)f32_bf16_fast(b[1]);
    r[6] = (short)f32_bf16_fast(b[2]); r[7] = (short)f32_bf16_fast(b[3]);
    return r;
}
__device__ inline bf16x4 cvt4(f32x4 a) {
    bf16x4 r;
    r[0] = (short)f32_bf16_fast(a[0]); r[1] = (short)f32_bf16_fast(a[1]);
    r[2] = (short)f32_bf16_fast(a[2]); r[3] = (short)f32_bf16_fast(a[3]);
    return r;
}

__global__ __launch_bounds__(256) void ft_main(
    const int* __restrict__ ids, const int* __restrict__ seqlen,
    const float* __restrict__ embed, const float* __restrict__ Wf,
    const float* __restrict__ bias, float* __restrict__ out)
{
    __shared__ unsigned char Wl[40960];

    const int tid  = threadIdx.x;
    const int wave = tid >> 6, lane = tid & 63;
    const int fr   = lane & 15, kg = lane >> 4;
    const int d    = blockIdx.x;                 // [0, 1024)

    // slot -> (real-tile index rt, col-half ch); pair (d, d+8) same XCD
    const int grp = d >> 4, sub = d & 15;
    const int rt  = grp * 8 + (sub & 7);         // [0, 512)
    const int ch  = sub >> 3;

    // locate rt among real tiles: batch b, local tile lt (register-only scan)
    int b = -1, lt = 0, acc = 0;
    #pragma unroll
    for (int bb = 0; bb < NB; ++bb) {
        int rb = (seqlen[bb] + 63) >> 6;         // real tiles in batch bb
        if (rt >= acc && rt < acc + rb) { b = bb; lt = rt - acc; }
        acc += rb;
    }

    if (b >= 0) {                                 // ---- real GEMM block ----
        const int tok0 = (b << 11) + (lt << 6);
        const int sl0  = seqlen[b];

        // -- A: id, then issue the ENTIRE gather burst (20 loads, no VALU) --
        const int token_a = tok0 + wave * 16 + fr;
        const int id = ids[token_a];
        const float* __restrict__ rp = embed + (long long)id * E;

        f32x4 r0[9], r1[9], t0v, t1v;
        #pragma unroll
        for (int s = 0; s < 9; ++s) {
            const int kb = s * 32 + kg * 8;       // <= 280; ends 287 < 300
            r0[s] = *(const f32x4*)(rp + kb);
            r1[s] = *(const f32x4*)(rp + kb + 4);
        }
        {   // tail loads: valid k 288..299, exact bounds
            f32x4 z4 = {0.f, 0.f, 0.f, 0.f};
            t0v = z4; t1v = z4;
            if (kg == 0)      { t0v = *(const f32x4*)(rp + 288); t1v = *(const f32x4*)(rp + 292); }
            else if (kg == 1) { t0v = *(const f32x4*)(rp + 296); }
        }

        // -- stage W rows [ch*64, +64) -> LDS fragment-major (overlaps gather) --
        const int R0 = ch * 64;
        #pragma unroll
        for (int i = 0; i < 20; ++i) {
            int g4 = tid + i * 256;               // [0, 5120) quads
            int r  = g4 / 80;
            int c4 = g4 - r * 80;
            int c0 = c4 * 4;                      // {0,4,...,316}
            f32x4 v = {0.f, 0.f, 0.f, 0.f};
            if (c0 < 300)                         // c0 <= 296: reads 296..299 exact
                v = *(const f32x4*)(Wf + (long long)(R0 + r) * E + c0);
            int s   = c0 >> 5;
            int kgg = (c0 & 31) >> 3;
            int h   = (c0 >> 2) & 1;
            int ni  = r >> 4;
            int fr2 = r & 15;
            int off = (((s * 4 + ni) * 16 + fr2) << 6) + (kgg << 4) + (h << 3);
            *(bf16x4*)(Wl + off) = cvt4(v);
        }

        // -- convert the gather burst to bf16 fragments --
        bf16x8 av[10];
        #pragma unroll
        for (int s = 0; s < 9; ++s) av[s] = cvt8(r0[s], r1[s]);
        av[9] = cvt8(t0v, t1v);
        __syncthreads();

        // -- MFMA: 10 k-steps x 4 ni, B from LDS (conflict-free b128) --
        f32x4 acc4[4];
        #pragma unroll
        for (int ni = 0; ni < 4; ++ni) acc4[ni] = (f32x4){0.f, 0.f, 0.f, 0.f};

        #pragma unroll
        for (int s = 0; s < 10; ++s) {
            #pragma unroll
            for (int ni = 0; ni < 4; ++ni) {
                bf16x8 bv = *(const bf16x8*)(Wl + ((((s * 4 + ni) * 16 + fr) << 6) + (kg << 4)));
                acc4[ni] = __builtin_amdgcn_mfma_f32_16x16x32_bf16(av[s], bv, acc4[ni], 0, 0, 0);
            }
        }

        // -- epilogue: +bias, per-row seq-mask, store --
        // C/D layout: col(=W row -> P) = lane&15, row(=token) = (lane>>4)*4 + j
        float bs[4];
        #pragma unroll
        for (int ni = 0; ni < 4; ++ni) bs[ni] = bias[ch * 64 + ni * 16 + fr];

        #pragma unroll
        for (int j = 0; j < 4; ++j) {
            int orow  = wave * 16 + kg * 4 + j;
            int token = tok0 + orow;
            int t     = token & (S - 1);
            bool valid = (t < sl0);
            #pragma unroll
            for (int ni = 0; ni < 4; ++ni) {
                float v = valid ? (acc4[ni][j] + bs[ni]) : 0.0f;
                out[(long long)token * P + ch * 64 + ni * 16 + fr] = v;
            }
        }
    }

    // ---- zero-fill share (ALL blocks, exactly even split) ----
    int rb0  = (seqlen[0]  + 63) >> 6,  rb1  = (seqlen[1]  + 63) >> 6,
        rb2  = (seqlen[2]  + 63) >> 6,  rb3  = (seqlen[3]  + 63) >> 6,
        rb4  = (seqlen[4]  + 63) >> 6,  rb5  = (seqlen[5]  + 63) >> 6,
        rb6  = (seqlen[6]  + 63) >> 6,  rb7  = (seqlen[7]  + 63) >> 6,
        rb8  = (seqlen[8]  + 63) >> 6,  rb9  = (seqlen[9]  + 63) >> 6,
        rb10 = (seqlen[10] + 63) >> 6,  rb11 = (seqlen[11] + 63) >> 6,
        rb12 = (seqlen[12] + 63) >> 6,  rb13 = (seqlen[13] + 63) >> 6,
        rb14 = (seqlen[14] + 63) >> 6,  rb15 = (seqlen[15] + 63) >> 6;
    int zp0 = 0;
    int zp1  = zp0  + ((S - (rb0  << 6)) << 5);
    int zp2  = zp1  + ((S - (rb1  << 6)) << 5);
    int zp3  = zp2  + ((S - (rb2  << 6)) << 5);
    int zp4  = zp3  + ((S - (rb3  << 6)) << 5);
    int zp5  = zp4  + ((S - (rb4  << 6)) << 5);
    int zp6  = zp5  + ((S - (rb5  << 6)) << 5);
    int zp7  = zp6  + ((S - (rb6  << 6)) << 5);
    int zp8  = zp7  + ((S - (rb7  << 6)) << 5);
    int zp9  = zp8  + ((S - (rb8  << 6)) << 5);
    int zp10 = zp9  + ((S - (rb9  << 6)) << 5);
    int zp11 = zp10 + ((S - (rb10 << 6)) << 5);
    int zp12 = zp11 + ((S - (rb11 << 6)) << 5);
    int zp13 = zp12 + ((S - (rb12 << 6)) << 5);
    int zp14 = zp13 + ((S - (rb13 << 6)) << 5);
    int zp15 = zp14 + ((S - (rb14 << 6)) << 5);
    int zp16 = zp15 + ((S - (rb15 << 6)) << 5);

    const int zq  = zp16;
    const int per = (zq + 1023) >> 10;           // quads per block
    int q0 = d * per;
    int q1 = q0 + per; if (q1 > zq) q1 = zq;

    for (int q = q0 + tid; q < q1; q += 256) {
        int base = 0, tk0 = 0;
        #define ZSEL(BB, LO, HI, RB) \
            if (q >= (LO) && q < (HI)) { base = (LO); tk0 = ((BB) << 11) + ((RB) << 6); }
        ZSEL(0,  zp0,  zp1,  rb0)  ZSEL(1,  zp1,  zp2,  rb1)
        ZSEL(2,  zp2,  zp3,  rb2)  ZSEL(3,  zp3,  zp4,  rb3)
        ZSEL(4,  zp4,  zp5,  rb4)  ZSEL(5,  zp5,  zp6,  rb5)
        ZSEL(6,  zp6,  zp7,  rb6)  ZSEL(7,  zp7,  zp8,  rb7)
        ZSEL(8,  zp8,  zp9,  rb8)  ZSEL(9,  zp9,  zp10, rb9)
        ZSEL(10, zp10, zp11, rb10) ZSEL(11, zp11, zp12, rb11)
        ZSEL(12, zp12, zp13, rb12) ZSEL(13, zp13, zp14, rb13)
        ZSEL(14, zp14, zp15, rb14) ZSEL(15, zp15, zp16, rb15)
        #undef ZSEL
        int lq    = q - base;
        int token = tk0 + (lq >> 5);
        int c     = (lq & 31) << 2;
        *(f32x4*)(out + (long long)token * P + c) = (f32x4){0.f, 0.f, 0.f, 0.f};
    }
}

extern "C" void kernel_launch(void* const* d_in, const int* in_sizes, int n_in,
                              void* d_out, int out_size, void* d_ws, size_t ws_size,
                              hipStream_t stream) {
    const int*   ids    = (const int*)d_in[0];
    const int*   sl     = (const int*)d_in[1];
    const float* embed  = (const float*)d_in[2];
    const float* W      = (const float*)d_in[3];
    const float* bias   = (const float*)d_in[4];
    float*       out    = (float*)d_out;

    ft_main<<<(BS / TM) * 2, 256, 0, stream>>>(ids, sl, embed, W, bias, out);
}